// Round 3
// baseline (410.059 us; speedup 1.0000x reference)
//
#include <hip/hip_runtime.h>

#define S_LEN 1024
#define HID   768
#define T_SZ  9
#define NEG_VAL (-1e12f)

typedef __bf16 bf16x8 __attribute__((ext_vector_type(8)));
typedef float  f32x4  __attribute__((ext_vector_type(4)));
typedef short  short8 __attribute__((ext_vector_type(8)));
typedef short  short4v __attribute__((ext_vector_type(4)));
typedef float  float4v __attribute__((ext_vector_type(4)));

__device__ __forceinline__ unsigned short f2bf(float f) {
    unsigned int u = __builtin_bit_cast(unsigned int, f);
    u += 0x7FFFu + ((u >> 16) & 1u);          // RNE
    return (unsigned short)(u >> 16);
}

// ---------------- kernel 0: rope tables ----------------
__global__ void k_tables(float* __restrict__ cosT, float* __restrict__ sinT) {
    int idx = blockIdx.x * 256 + threadIdx.x;     // 1024*64 entries
    int s = idx >> 6;
    int d = idx & 63;
    float theta = powf(10000.0f, -2.0f * (float)(d >> 1) * (1.0f / 64.0f));
    float ang = (float)s * theta;
    float sv, cv;
    sincosf(ang, &sv, &cv);
    cosT[idx] = cv;
    sinT[idx] = sv;
}

// ---------------- kernel 1: projection GEMM + bias + RoPE -> q/k bf16 ----------------
// C tile 128x128: rows = 128 of (b*S+s), cols = one full t block (D*2 = 128).
__global__ __launch_bounds__(256) void k_proj_rope(
    const float* __restrict__ hidden,
    const float* __restrict__ W,
    const float* __restrict__ bias,
    const float* __restrict__ cosT,
    const float* __restrict__ sinT,
    unsigned short* __restrict__ qout,
    unsigned short* __restrict__ kout)
{
    __shared__ union {
        struct { unsigned short A[128 * 64]; unsigned short B[128 * 64]; } st;
        unsigned short Tr[128 * 136];   // col-major bounce: [col][row], stride 136
    } sm;

    int tid = threadIdx.x;
    int mt = blockIdx.x / 9;
    int t  = blockIdx.x % 9;
    int m0 = mt * 128;
    int n0 = t * 128;

    int lane = tid & 63;
    int wave = tid >> 6;
    int lr = lane & 15;
    int lq = lane >> 4;
    int wrow = wave * 32;

    float bv[8];
    #pragma unroll
    for (int fn = 0; fn < 8; ++fn) bv[fn] = bias[n0 + fn * 16 + lr];

    int srow = tid >> 1;
    int half = tid & 1;
    const float* aSrc = hidden + (size_t)(m0 + srow) * HID + half * 32;
    const float* bSrc = W      + (size_t)(n0 + srow) * HID + half * 32;

    f32x4 acc[2][8];
    #pragma unroll
    for (int i = 0; i < 2; ++i)
        #pragma unroll
        for (int j = 0; j < 8; ++j) acc[i][j] = (f32x4){0.f, 0.f, 0.f, 0.f};

    for (int kk = 0; kk < HID / 64; ++kk) {
        __syncthreads();
        // stage A (hidden) and B (W rows) as bf16, XOR-swizzled 16B segs
        #pragma unroll
        for (int which = 0; which < 2; ++which) {
            const float* src = which ? bSrc : aSrc;
            unsigned short* dst = which ? sm.st.B : sm.st.A;
            #pragma unroll
            for (int sgi = 0; sgi < 4; ++sgi) {
                float4v v0 = *(const float4v*)(src + kk * 64 + sgi * 8);
                float4v v1 = *(const float4v*)(src + kk * 64 + sgi * 8 + 4);
                short8 p;
                p[0] = (short)f2bf(v0[0]); p[1] = (short)f2bf(v0[1]);
                p[2] = (short)f2bf(v0[2]); p[3] = (short)f2bf(v0[3]);
                p[4] = (short)f2bf(v1[0]); p[5] = (short)f2bf(v1[1]);
                p[6] = (short)f2bf(v1[2]); p[7] = (short)f2bf(v1[3]);
                int seg = half * 4 + sgi;
                *(short8*)&dst[srow * 64 + ((seg ^ (srow & 7)) * 8)] = p;
            }
        }
        __syncthreads();
        #pragma unroll
        for (int kb = 0; kb < 2; ++kb) {
            bf16x8 af[2];
            #pragma unroll
            for (int fm = 0; fm < 2; ++fm) {
                int r = wrow + fm * 16 + lr;
                int seg = kb * 4 + lq;
                af[fm] = *(const bf16x8*)&sm.st.A[r * 64 + ((seg ^ (r & 7)) * 8)];
            }
            #pragma unroll
            for (int fn = 0; fn < 8; ++fn) {
                int r = fn * 16 + lr;
                int seg = kb * 4 + lq;
                bf16x8 bfr = *(const bf16x8*)&sm.st.B[r * 64 + ((seg ^ (r & 7)) * 8)];
                acc[0][fn] = __builtin_amdgcn_mfma_f32_16x16x32_bf16(af[0], bfr, acc[0][fn], 0, 0, 0);
                acc[1][fn] = __builtin_amdgcn_mfma_f32_16x16x32_bf16(af[1], bfr, acc[1][fn], 0, 0, 0);
            }
        }
    }
    __syncthreads();

    // bounce C (bias added) to col-major LDS as bf16; rows j=0..3 are contiguous -> b64 write
    #pragma unroll
    for (int fm = 0; fm < 2; ++fm) {
        #pragma unroll
        for (int fn = 0; fn < 8; ++fn) {
            int col = fn * 16 + lr;
            int r0 = wrow + fm * 16 + lq * 4;
            short4v pk;
            #pragma unroll
            for (int j = 0; j < 4; ++j) pk[j] = (short)f2bf(acc[fm][fn][j] + bv[fn]);
            *(short4v*)&sm.Tr[col * 136 + r0] = pk;
        }
    }
    __syncthreads();

    // RoPE + transpose write: thread owns dim d for 32 rows
    int d = tid & 63;
    int grp = tid >> 6;
    int cq = 2 * d, ck = 2 * d + 1;
    int pq = (d < 32) ? (4 * d + 2) : (4 * (d - 32));
    int pk2 = pq + 1;
    float sgn = (d < 32) ? -1.0f : 1.0f;
    #pragma unroll
    for (int ch = 0; ch < 4; ++ch) {
        int r0 = grp * 32 + ch * 8;
        bf16x8 xq = *(const bf16x8*)&sm.Tr[cq * 136 + r0];
        bf16x8 xk = *(const bf16x8*)&sm.Tr[ck * 136 + r0];
        bf16x8 yq = *(const bf16x8*)&sm.Tr[pq * 136 + r0];
        bf16x8 yk = *(const bf16x8*)&sm.Tr[pk2 * 136 + r0];
        #pragma unroll
        for (int rr = 0; rr < 8; ++rr) {
            int gm = m0 + r0 + rr;
            int s  = gm & (S_LEN - 1);
            int bb = gm >> 10;
            float cv = cosT[s * 64 + d];
            float sv = sinT[s * 64 + d];
            float qv = (float)xq[rr] * cv + sgn * (float)yq[rr] * sv;
            float kv = (float)xk[rr] * cv + sgn * (float)yk[rr] * sv;
            size_t ob = (((size_t)bb * T_SZ + t) * S_LEN + s) * 64 + d;
            qout[ob] = f2bf(qv);
            kout[ob] = f2bf(kv);
        }
    }
}

// ---------------- kernel 2: logits = q.k^T per (b,t), mask epilogue ----------------
__global__ __launch_bounds__(256) void k_logits(
    const unsigned short* __restrict__ q,
    const unsigned short* __restrict__ k,
    const int* __restrict__ mask,
    float* __restrict__ out)
{
    int tid = threadIdx.x;
    int bt  = blockIdx.x >> 6;
    int rem = blockIdx.x & 63;
    int ti = rem >> 3;
    int tj = rem & 7;
    size_t obase = ((size_t)bt * S_LEN + (size_t)ti * 128) * S_LEN + tj * 128;

    if (ti > tj) {  // fully below diagonal: pure NEG fill
        float4v nv = {NEG_VAL, NEG_VAL, NEG_VAL, NEG_VAL};
        #pragma unroll
        for (int it = 0; it < 16; ++it) {
            int idx = it * 256 + tid;
            int r = idx >> 5;
            int c4 = idx & 31;
            *(float4v*)&out[obase + (size_t)r * S_LEN + c4 * 4] = nv;
        }
        return;
    }

    __shared__ unsigned short As[128 * 64];
    __shared__ unsigned short Bs[128 * 64];
    __shared__ int mi[128], mj[128];

    int b = bt / 9;
    if (tid < 128) mi[tid] = mask[b * S_LEN + ti * 128 + tid];
    else           mj[tid - 128] = mask[b * S_LEN + tj * 128 + (tid - 128)];

    const unsigned short* qsrc = q + ((size_t)bt * S_LEN + (size_t)ti * 128) * 64;
    const unsigned short* ksrc = k + ((size_t)bt * S_LEN + (size_t)tj * 128) * 64;
    #pragma unroll
    for (int it = 0; it < 4; ++it) {
        int r = it * 32 + (tid >> 3);
        int seg = tid & 7;
        short8 vq = *(const short8*)&qsrc[r * 64 + seg * 8];
        short8 vk = *(const short8*)&ksrc[r * 64 + seg * 8];
        int sw = (seg ^ (r & 7)) * 8;
        *(short8*)&As[r * 64 + sw] = vq;
        *(short8*)&Bs[r * 64 + sw] = vk;
    }
    __syncthreads();

    int lane = tid & 63;
    int wave = tid >> 6;
    int lr = lane & 15;
    int lq = lane >> 4;
    int wrow = wave * 32;

    f32x4 acc[2][8];
    #pragma unroll
    for (int i = 0; i < 2; ++i)
        #pragma unroll
        for (int j = 0; j < 8; ++j) acc[i][j] = (f32x4){0.f, 0.f, 0.f, 0.f};

    #pragma unroll
    for (int kb = 0; kb < 2; ++kb) {
        bf16x8 af[2];
        #pragma unroll
        for (int fm = 0; fm < 2; ++fm) {
            int r = wrow + fm * 16 + lr;
            int seg = kb * 4 + lq;
            af[fm] = *(const bf16x8*)&As[r * 64 + ((seg ^ (r & 7)) * 8)];
        }
        #pragma unroll
        for (int fn = 0; fn < 8; ++fn) {
            int r = fn * 16 + lr;
            int seg = kb * 4 + lq;
            bf16x8 bfr = *(const bf16x8*)&Bs[r * 64 + ((seg ^ (r & 7)) * 8)];
            acc[0][fn] = __builtin_amdgcn_mfma_f32_16x16x32_bf16(af[0], bfr, acc[0][fn], 0, 0, 0);
            acc[1][fn] = __builtin_amdgcn_mfma_f32_16x16x32_bf16(af[1], bfr, acc[1][fn], 0, 0, 0);
        }
    }

    #pragma unroll
    for (int fm = 0; fm < 2; ++fm) {
        #pragma unroll
        for (int j = 0; j < 4; ++j) {
            int il = wrow + fm * 16 + lq * 4 + j;
            int gi = ti * 128 + il;
            int mrow = mi[il];
            size_t rbase = obase + (size_t)il * S_LEN;
            #pragma unroll
            for (int fn = 0; fn < 8; ++fn) {
                int jl = fn * 16 + lr;
                int gj = tj * 128 + jl;
                bool ok = (gi <= gj) && mrow && mj[jl];
                out[rbase + jl] = ok ? acc[fm][fn][j] : NEG_VAL;
            }
        }
    }
}

extern "C" void kernel_launch(void* const* d_in, const int* in_sizes, int n_in,
                              void* d_out, int out_size, void* d_ws, size_t ws_size,
                              hipStream_t stream) {
    const float* hidden = (const float*)d_in[0];
    const int*   mask   = (const int*)d_in[1];
    const float* W      = (const float*)d_in[2];
    const float* bias   = (const float*)d_in[3];
    float* out = (float*)d_out;
    int Bsz = in_sizes[0] / (S_LEN * HID);

    char* ws = (char*)d_ws;
    float* cosT = (float*)ws;
    float* sinT = (float*)(ws + (size_t)S_LEN * 64 * 4);
    unsigned short* qb = (unsigned short*)(ws + 2ull * S_LEN * 64 * 4);
    size_t qkElems = (size_t)Bsz * T_SZ * S_LEN * 64;
    unsigned short* kb = qb + qkElems;

    k_tables<<<dim3(S_LEN * 64 / 256), dim3(256), 0, stream>>>(cosT, sinT);
    k_proj_rope<<<dim3(Bsz * 8 * 9), dim3(256), 0, stream>>>(hidden, W, bias, cosT, sinT, qb, kb);
    k_logits<<<dim3(Bsz * T_SZ * 64), dim3(256), 0, stream>>>(qb, kb, mask, out);
}

// Round 4
// 378.627 us; speedup vs baseline: 1.0830x; 1.0830x over previous
//
#include <hip/hip_runtime.h>

#define S_LEN 1024
#define HID   768
#define T_SZ  9
#define NEG_VAL (-1e12f)

typedef __bf16 bf16x8 __attribute__((ext_vector_type(8)));
typedef float  f32x4  __attribute__((ext_vector_type(4)));
typedef short  short8 __attribute__((ext_vector_type(8)));
typedef short  short4v __attribute__((ext_vector_type(4)));
typedef float  float4v __attribute__((ext_vector_type(4)));

__device__ __forceinline__ unsigned short f2bf(float f) {
    unsigned int u = __builtin_bit_cast(unsigned int, f);
    u += 0x7FFFu + ((u >> 16) & 1u);          // RNE
    return (unsigned short)(u >> 16);
}

// async global->LDS, 16B per lane, linear dest (wave-uniform base + lane*16)
__device__ __forceinline__ void gload_lds16(const void* g, void* l) {
    __builtin_amdgcn_global_load_lds(
        (const __attribute__((address_space(1))) unsigned int*)g,
        (__attribute__((address_space(3))) unsigned int*)l,
        16, 0, 0);
}

// ---------------- kernel A: fp32 -> bf16 bulk convert ----------------
__global__ __launch_bounds__(256) void k_convert(const float* __restrict__ src,
                                                 unsigned short* __restrict__ dst,
                                                 int n8) {
    int i = blockIdx.x * 256 + threadIdx.x;
    if (i >= n8) return;
    float4v a = *((const float4v*)src + (size_t)i * 2);
    float4v b = *((const float4v*)src + (size_t)i * 2 + 1);
    short8 o;
    o[0] = (short)f2bf(a[0]); o[1] = (short)f2bf(a[1]);
    o[2] = (short)f2bf(a[2]); o[3] = (short)f2bf(a[3]);
    o[4] = (short)f2bf(b[0]); o[5] = (short)f2bf(b[1]);
    o[6] = (short)f2bf(b[2]); o[7] = (short)f2bf(b[3]);
    *(short8*)(dst + (size_t)i * 8) = o;
}

// ---------------- kernel 0: rope tables ----------------
__global__ void k_tables(float* __restrict__ cosT, float* __restrict__ sinT) {
    int idx = blockIdx.x * 256 + threadIdx.x;     // 1024*64 entries
    int s = idx >> 6;
    int d = idx & 63;
    // 10000^(-(d>>1)/32) = 2^(-log2(1e4)*(d>>1)/32)
    float theta = exp2f(-13.2877123795f * (float)(d >> 1) * (1.0f / 32.0f));
    float ang = (float)s * theta;
    float sv, cv;
    sincosf(ang, &sv, &cv);
    cosT[idx] = cv;
    sinT[idx] = sv;
}

// ---------------- kernel 1: projection GEMM + bias + RoPE -> q/k bf16 ----------------
// C tile 128x128: rows = 128 of (b*S+s), cols = one full t block (D*2 = 128).
__global__ __launch_bounds__(256) void k_proj_rope(
    const unsigned short* __restrict__ hidB,   // [B*S][768] bf16
    const unsigned short* __restrict__ wB,     // [1152][768] bf16
    const float* __restrict__ bias,
    const float* __restrict__ cosT,
    const float* __restrict__ sinT,
    unsigned short* __restrict__ qout,
    unsigned short* __restrict__ kout)
{
    __shared__ union __align__(16) {
        struct { unsigned short A[128 * 64]; unsigned short B[128 * 64]; } st;
        unsigned short Tr[128 * 136];   // col-major bounce: [col][row], stride 136
    } sm;

    int tid = threadIdx.x;
    int mt = blockIdx.x / 9;
    int t  = blockIdx.x % 9;
    int m0 = mt * 128;
    int n0 = t * 128;

    int lane = tid & 63;
    int wave = tid >> 6;
    int lr = lane & 15;
    int lq = lane >> 4;
    int wrow = wave * 32;

    float bv[8];
    #pragma unroll
    for (int fn = 0; fn < 8; ++fn) bv[fn] = bias[n0 + fn * 16 + lr];

    // per-lane pre-swizzled staging sources: LDS linear slot (gsi) gets data seg = slot^ (r&7)
    const unsigned short* aSrc[4];
    const unsigned short* bSrc[4];
    #pragma unroll
    for (int it = 0; it < 4; ++it) {
        int gsi = (wave * 4 + it) * 64 + lane;
        int r = gsi >> 3;
        int sw = gsi & 7;
        int seg8 = (sw ^ (r & 7)) << 3;
        aSrc[it] = hidB + (size_t)(m0 + r) * HID + seg8;
        bSrc[it] = wB  + (size_t)(n0 + r) * HID + seg8;
    }

    f32x4 acc[2][8];
    #pragma unroll
    for (int i = 0; i < 2; ++i)
        #pragma unroll
        for (int j = 0; j < 8; ++j) acc[i][j] = (f32x4){0.f, 0.f, 0.f, 0.f};

    for (int kk = 0; kk < HID / 64; ++kk) {
        __syncthreads();
        #pragma unroll
        for (int it = 0; it < 4; ++it) {
            gload_lds16(aSrc[it] + kk * 64, &sm.st.A[(wave * 4 + it) * 512]);
            gload_lds16(bSrc[it] + kk * 64, &sm.st.B[(wave * 4 + it) * 512]);
        }
        __syncthreads();   // compiler drains vmcnt(0) before barrier -> LDS ready
        #pragma unroll
        for (int kb = 0; kb < 2; ++kb) {
            bf16x8 af[2];
            #pragma unroll
            for (int fm = 0; fm < 2; ++fm) {
                int r = wrow + fm * 16 + lr;
                int seg = kb * 4 + lq;
                af[fm] = *(const bf16x8*)&sm.st.A[r * 64 + ((seg ^ (r & 7)) * 8)];
            }
            #pragma unroll
            for (int fn = 0; fn < 8; ++fn) {
                int r = fn * 16 + lr;
                int seg = kb * 4 + lq;
                bf16x8 bfr = *(const bf16x8*)&sm.st.B[r * 64 + ((seg ^ (r & 7)) * 8)];
                acc[0][fn] = __builtin_amdgcn_mfma_f32_16x16x32_bf16(af[0], bfr, acc[0][fn], 0, 0, 0);
                acc[1][fn] = __builtin_amdgcn_mfma_f32_16x16x32_bf16(af[1], bfr, acc[1][fn], 0, 0, 0);
            }
        }
    }
    __syncthreads();

    // bounce C (bias added) to col-major LDS as bf16; rows j=0..3 contiguous -> b64 write
    #pragma unroll
    for (int fm = 0; fm < 2; ++fm) {
        #pragma unroll
        for (int fn = 0; fn < 8; ++fn) {
            int col = fn * 16 + lr;
            int r0 = wrow + fm * 16 + lq * 4;
            short4v pk;
            #pragma unroll
            for (int j = 0; j < 4; ++j) pk[j] = (short)f2bf(acc[fm][fn][j] + bv[fn]);
            *(short4v*)&sm.Tr[col * 136 + r0] = pk;
        }
    }
    __syncthreads();

    // RoPE + transpose write: thread owns dim d for 32 rows
    int d = tid & 63;
    int grp = tid >> 6;
    int cq = 2 * d, ck = 2 * d + 1;
    int pq = (d < 32) ? (4 * d + 2) : (4 * (d - 32));
    int pk2 = pq + 1;
    float sgn = (d < 32) ? -1.0f : 1.0f;
    #pragma unroll
    for (int ch = 0; ch < 4; ++ch) {
        int r0 = grp * 32 + ch * 8;
        bf16x8 xq = *(const bf16x8*)&sm.Tr[cq * 136 + r0];
        bf16x8 xk = *(const bf16x8*)&sm.Tr[ck * 136 + r0];
        bf16x8 yq = *(const bf16x8*)&sm.Tr[pq * 136 + r0];
        bf16x8 yk = *(const bf16x8*)&sm.Tr[pk2 * 136 + r0];
        #pragma unroll
        for (int rr = 0; rr < 8; ++rr) {
            int gm = m0 + r0 + rr;
            int s  = gm & (S_LEN - 1);
            int bb = gm >> 10;
            float cv = cosT[s * 64 + d];
            float sv = sinT[s * 64 + d];
            float qv = (float)xq[rr] * cv + sgn * (float)yq[rr] * sv;
            float kv = (float)xk[rr] * cv + sgn * (float)yk[rr] * sv;
            size_t ob = (((size_t)bb * T_SZ + t) * S_LEN + s) * 64 + d;
            qout[ob] = f2bf(qv);
            kout[ob] = f2bf(kv);
        }
    }
}

// ---------------- kernel 2: logits = q.k^T per (b,t), mask epilogue ----------------
// Swapped-operand MFMA: D = K·Q^T tile => lane&15 = output ROW, reg = output COL
// -> each lane owns 4 consecutive output columns -> float4 stores.
__global__ __launch_bounds__(256) void k_logits(
    const unsigned short* __restrict__ q,
    const unsigned short* __restrict__ k,
    const int* __restrict__ mask,
    float* __restrict__ out)
{
    int tid = threadIdx.x;
    int bt  = blockIdx.x >> 6;
    int rem = blockIdx.x & 63;
    int ti = rem >> 3;
    int tj = rem & 7;
    size_t obase = ((size_t)bt * S_LEN + (size_t)ti * 128) * S_LEN + tj * 128;

    if (ti > tj) {  // fully below diagonal: pure NEG fill
        float4v nv = {NEG_VAL, NEG_VAL, NEG_VAL, NEG_VAL};
        #pragma unroll
        for (int it = 0; it < 16; ++it) {
            int idx = it * 256 + tid;
            int r = idx >> 5;
            int c4 = idx & 31;
            __builtin_nontemporal_store(nv, (float4v*)&out[obase + (size_t)r * S_LEN + c4 * 4]);
        }
        return;
    }

    __shared__ __align__(16) unsigned short As[128 * 64];   // q tile
    __shared__ __align__(16) unsigned short Bs[128 * 64];   // k tile
    __shared__ int mi[128], mj[128];

    int b = bt / 9;
    if (tid < 128) mi[tid] = mask[b * S_LEN + ti * 128 + tid];
    else           mj[tid - 128] = mask[b * S_LEN + tj * 128 + (tid - 128)];

    const unsigned short* qsrc = q + ((size_t)bt * S_LEN + (size_t)ti * 128) * 64;
    const unsigned short* ksrc = k + ((size_t)bt * S_LEN + (size_t)tj * 128) * 64;

    int lane = tid & 63;
    int wave = tid >> 6;
    #pragma unroll
    for (int it = 0; it < 4; ++it) {
        int gsi = (wave * 4 + it) * 64 + lane;
        int r = gsi >> 3;
        int sw = gsi & 7;
        int off = r * 64 + ((sw ^ (r & 7)) << 3);
        gload_lds16(qsrc + off, &As[(wave * 4 + it) * 512]);
        gload_lds16(ksrc + off, &Bs[(wave * 4 + it) * 512]);
    }
    __syncthreads();

    int lr = lane & 15;
    int lq = lane >> 4;
    int wrow = wave * 32;

    f32x4 acc[2][8];
    #pragma unroll
    for (int i = 0; i < 2; ++i)
        #pragma unroll
        for (int j = 0; j < 8; ++j) acc[i][j] = (f32x4){0.f, 0.f, 0.f, 0.f};

    #pragma unroll
    for (int kb = 0; kb < 2; ++kb) {
        bf16x8 qf[2];
        #pragma unroll
        for (int fi = 0; fi < 2; ++fi) {
            int r = wrow + fi * 16 + lr;
            int seg = kb * 4 + lq;
            qf[fi] = *(const bf16x8*)&As[r * 64 + ((seg ^ (r & 7)) * 8)];
        }
        #pragma unroll
        for (int fn = 0; fn < 8; ++fn) {
            int r = fn * 16 + lr;
            int seg = kb * 4 + lq;
            bf16x8 kf = *(const bf16x8*)&Bs[r * 64 + ((seg ^ (r & 7)) * 8)];
            acc[0][fn] = __builtin_amdgcn_mfma_f32_16x16x32_bf16(kf, qf[0], acc[0][fn], 0, 0, 0);
            acc[1][fn] = __builtin_amdgcn_mfma_f32_16x16x32_bf16(kf, qf[1], acc[1][fn], 0, 0, 0);
        }
    }

    // lane owns: row i = wrow + fi*16 + lr; cols j = fn*16 + lq*4 + e
    #pragma unroll
    for (int fi = 0; fi < 2; ++fi) {
        int il = wrow + fi * 16 + lr;
        int gi = ti * 128 + il;
        bool mrow = mi[il] != 0;
        size_t rbase = obase + (size_t)il * S_LEN;
        #pragma unroll
        for (int fn = 0; fn < 8; ++fn) {
            int j0 = fn * 16 + lq * 4;
            int gj0 = tj * 128 + j0;
            float4v v;
            #pragma unroll
            for (int e = 0; e < 4; ++e) {
                bool ok = mrow && (mj[j0 + e] != 0) && (gi <= gj0 + e);
                v[e] = ok ? acc[fi][fn][e] : NEG_VAL;
            }
            __builtin_nontemporal_store(v, (float4v*)&out[rbase + j0]);
        }
    }
}

extern "C" void kernel_launch(void* const* d_in, const int* in_sizes, int n_in,
                              void* d_out, int out_size, void* d_ws, size_t ws_size,
                              hipStream_t stream) {
    const float* hidden = (const float*)d_in[0];
    const int*   mask   = (const int*)d_in[1];
    const float* W      = (const float*)d_in[2];
    const float* bias   = (const float*)d_in[3];
    float* out = (float*)d_out;
    int Bsz = in_sizes[0] / (S_LEN * HID);

    char* ws = (char*)d_ws;
    float* cosT = (float*)ws;
    float* sinT = (float*)(ws + (size_t)S_LEN * 64 * 4);
    unsigned short* hidB = (unsigned short*)(ws + 2ull * S_LEN * 64 * 4);
    size_t hidElems = (size_t)Bsz * S_LEN * HID;
    unsigned short* wB = hidB + hidElems;
    size_t wElems = (size_t)2 * T_SZ * 64 * HID;
    unsigned short* qb = wB + wElems;
    size_t qkElems = (size_t)Bsz * T_SZ * S_LEN * 64;
    unsigned short* kb = qb + qkElems;

    int n8h = (int)(hidElems / 8);
    int n8w = (int)(wElems / 8);
    k_convert<<<dim3((n8h + 255) / 256), dim3(256), 0, stream>>>(hidden, hidB, n8h);
    k_convert<<<dim3((n8w + 255) / 256), dim3(256), 0, stream>>>(W, wB, n8w);
    k_tables<<<dim3(S_LEN * 64 / 256), dim3(256), 0, stream>>>(cosT, sinT);
    k_proj_rope<<<dim3(Bsz * 8 * 9), dim3(256), 0, stream>>>(hidB, wB, bias, cosT, sinT, qb, kb);
    k_logits<<<dim3(Bsz * T_SZ * 64), dim3(256), 0, stream>>>(qb, kb, mask, out);
}